// Round 8
// baseline (267.190 us; speedup 1.0000x reference)
//
#include <hip/hip_runtime.h>
#include <hip/hip_bf16.h>
#include <stdint.h>

#define DEVINLINE __device__ __forceinline__

typedef __attribute__((ext_vector_type(4))) float f32x4;
typedef __attribute__((ext_vector_type(8))) short bf16x8;

DEVINLINE unsigned short f2bf(float f) {
    union { float f; uint32_t u; } v; v.f = f;
    uint32_t u = v.u;
    uint32_t rounding = 0x7FFFu + ((u >> 16) & 1u);
    u += rounding;
    return (unsigned short)(u >> 16);
}

DEVINLINE float bf2f(unsigned short h) {
    union { uint32_t u; float f; } v; v.u = ((uint32_t)h) << 16;
    return v.f;
}

// ---------------- fp32 -> bf16 elementwise convert ----------------
__global__ void cvt_f32_bf16(const float* __restrict__ in,
                             unsigned short* __restrict__ out, int n) {
    int i = (blockIdx.x * blockDim.x + threadIdx.x) * 4;
    int stride = gridDim.x * blockDim.x * 4;
    for (; i < n; i += stride) {
        float4 v = *reinterpret_cast<const float4*>(in + i);
        ushort4 o;
        o.x = f2bf(v.x); o.y = f2bf(v.y); o.z = f2bf(v.z); o.w = f2bf(v.w);
        *reinterpret_cast<ushort4*>(out + i) = o;
    }
}

// ---------------- fp32 [R][C] -> bf16 [C][R] transpose ----------------
__global__ void transpose_cvt(const float* __restrict__ in,
                              unsigned short* __restrict__ out,
                              int R, int Ccols) {
    __shared__ float tile[32][33];
    int c0 = blockIdx.x * 32, r0 = blockIdx.y * 32;
    int tx = threadIdx.x, ty = threadIdx.y; // 32 x 8
    #pragma unroll
    for (int j = 0; j < 32; j += 8)
        tile[ty + j][tx] = in[(size_t)(r0 + ty + j) * Ccols + c0 + tx];
    __syncthreads();
    #pragma unroll
    for (int j = 0; j < 32; j += 8)
        out[(size_t)(c0 + ty + j) * R + r0 + tx] = f2bf(tile[tx][ty + j]);
}

// ============ 256x256 bf16 GEMM: A via LDS (swizzled), B direct global->reg ============
// 8 waves (2M x 4N), BK=64. LDS holds ONLY A: 2 x 32 KiB double buffer.
// LDS traffic/tile: 128 KB reads + 32 KB writes (< MFMA floor) vs 256 KB before.
// Phase p = { MMA(quadrant); reads/issues for later phases; [stage]; s_barrier }.
// A-landing fences are implicit: compiler's vmcnt wait on the B-register loads
// (in-order retirement) forces older A-stage loads done; barrier propagates.

#define GLD(srcp, dstp) __builtin_amdgcn_global_load_lds( \
    (const __attribute__((address_space(1))) void*)(srcp), \
    (__attribute__((address_space(3))) void*)(dstp), 16, 0, 0)

// stage full A tile (256 rows x 64 cols bf16) = 4 GLD x 8 waves
#define STAGE4(P, kkE) do { \
    const unsigned short* _s = aSrc + (kkE); \
    unsigned short* _d = lds + (P) * 16384 + wid * 512; \
    GLD(_s, _d); \
    GLD(_s + (size_t)64  * K, _d + 4096); \
    GLD(_s + (size_t)128 * K, _d + 8192); \
    GLD(_s + (size_t)192 * K, _d + 12288); } while (0)

#define RD_A(dst, AS0, AS1, h) do { _Pragma("unroll") \
    for (int _i = 0; _i < 4; ++_i) { \
        dst[_i][0] = *(const bf16x8*)((AS0) + ((h) * 8192 + _i * 2048)); \
        dst[_i][1] = *(const bf16x8*)((AS1) + ((h) * 8192 + _i * 2048)); } } while (0)

// B fragments straight from global (16B-contiguous rows of B^T)
#define RDG_BA(kt) do { \
    bA[0][0] = *(const bf16x8*)(gB00 + (kt)); bA[0][1] = *(const bf16x8*)(gB00 + (kt) + 32); \
    bA[1][0] = *(const bf16x8*)(gB01 + (kt)); bA[1][1] = *(const bf16x8*)(gB01 + (kt) + 32); } while (0)
#define RDG_BB(kt) do { \
    bB[0][0] = *(const bf16x8*)(gB10 + (kt)); bB[0][1] = *(const bf16x8*)(gB10 + (kt) + 32); \
    bB[1][0] = *(const bf16x8*)(gB11 + (kt)); bB[1][1] = *(const bf16x8*)(gB11 + (kt) + 32); } while (0)

#define MMA(aX, bY, mh, nh) do { \
    __builtin_amdgcn_s_setprio(1); \
    _Pragma("unroll") for (int _i = 0; _i < 4; ++_i) { \
    _Pragma("unroll") for (int _j = 0; _j < 2; ++_j) { \
        acc[(mh)*4+_i][(nh)*2+_j] = __builtin_amdgcn_mfma_f32_16x16x32_bf16( \
            aX[_i][0], bY[_j][0], acc[(mh)*4+_i][(nh)*2+_j], 0, 0, 0); \
        acc[(mh)*4+_i][(nh)*2+_j] = __builtin_amdgcn_mfma_f32_16x16x32_bf16( \
            aX[_i][1], bY[_j][1], acc[(mh)*4+_i][(nh)*2+_j], 0, 0, 0); } } \
    __builtin_amdgcn_s_setprio(0); } while (0)

#define BAR() asm volatile("s_barrier" ::: "memory")

// One K-tile. ktC/ktN = element col of tile t / t+1 (clamped); kkA = stage col (t+2, clamped).
// p0: MMA(0,0); issue bB-glb(t,nh1);              BAR
// p1: MMA(0,1); read aB-lds(cur,h1);              BAR
// p2: MMA(1,0); issue bA-glb(t+1,nh0);            BAR
// p3: MMA(1,1); read aA-lds(next,h0); stage A(t+2); BAR
#define KTILE(AS0c, AS1c, AS0n, AS1n, Pc, ktC, ktN, kkA) do { \
    MMA(aA, bA, 0, 0); \
    RDG_BB(ktC); \
    BAR(); \
    MMA(aA, bB, 0, 1); \
    RD_A(aB, AS0c, AS1c, 1); \
    BAR(); \
    MMA(aB, bA, 1, 0); \
    RDG_BA(ktN); \
    BAR(); \
    MMA(aB, bB, 1, 1); \
    RD_A(aA, AS0n, AS1n, 0); \
    STAGE4(Pc, kkA); \
    BAR(); } while (0)

template <bool OUT_BF16>
__launch_bounds__(512, 2)
__global__ void gemm256(const unsigned short* __restrict__ A,
                        const unsigned short* __restrict__ Bt,
                        const float* __restrict__ bias,
                        void* __restrict__ Cout,
                        int M, int N, int K, int NTN) {
    __shared__ unsigned short lds[32768]; // 64 KiB: 2 buf x A 256x64
    const int NT = K >> 6;                // K-tiles (even, >= 2)

    int t = threadIdx.x;
    int wid = t >> 6, lane = t & 63;
    int wr = wid >> 2, wc = wid & 3;
    int fr = lane & 15, fq = lane >> 4;

    // XCD-aware block swizzle (grid % 8 == 0)
    int nwg = gridDim.x, bid = blockIdx.x;
    int cpx = nwg >> 3;
    int swz = (bid & 7) * cpx + (bid >> 3);
    int tm = swz / NTN, tn = swz % NTN;
    int bm = tm * 256, bn = tn * 256;

    // A staging source (per-lane, pre-swizzled 16B slot)
    int rowl = t >> 3, col8 = t & 7;
    int swzcol = (col8 ^ (rowl & 7)) << 3;
    const unsigned short* aSrc = A + (size_t)(bm + rowl) * K + swzcol;

    // B fragment base pointers (global, no swizzle)
    const unsigned short* gB00 = Bt + (size_t)(bn + wc * 64 + fr) * K + fq * 8;
    const unsigned short* gB01 = gB00 + (size_t)16 * K;
    const unsigned short* gB10 = gB00 + (size_t)32 * K;
    const unsigned short* gB11 = gB00 + (size_t)48 * K;

    // A ds_read swizzled base pointers (row&7 == fr&7 for all fragment rows)
    int swzm = (fr & 7) << 3;
    int colS0 = (fq << 3) ^ swzm;
    int colS1 = (32 | (fq << 3)) ^ swzm;

    char* ldsb = (char*)lds;
    char* A00 = ldsb + ((wr * 128 + fr) << 7) + 2 * colS0;
    char* A10 = ldsb + ((wr * 128 + fr) << 7) + 2 * colS1;
    char* A01 = A00 + 32768;
    char* A11 = A10 + 32768;

    f32x4 acc[8][4] = {};
    bf16x8 aA[4][2], aB[4][2], bA[2][2], bB[2][2];

    // ---- prologue: bA(0) global; stage A(0), A(1) ----
    RDG_BA(0);                 // loads 1-4
    STAGE4(0, 0);              // loads 5-8   A(0)
    STAGE4(1, 64);             // loads 9-12  A(1)
    asm volatile("s_waitcnt vmcnt(4)" ::: "memory"); // bA(0) + A(0) landed
    BAR();
    RD_A(aA, A00, A10, 0);     // A(0) h=0

    for (int tau = 0; tau < NT; tau += 2) {
        int kt0 = tau << 6;
        int kt1 = (tau + 1) << 6;
        int kt2 = ((tau + 2 < NT) ? (tau + 2) : (NT - 1)) << 6;
        int kt3 = ((tau + 3 < NT) ? (tau + 3) : (NT - 1)) << 6;
        KTILE(A00, A10, A01, A11, 0, kt0, kt1, kt2);
        KTILE(A01, A11, A00, A10, 1, kt1, kt2, kt3);
    }
    asm volatile("s_waitcnt vmcnt(0)" ::: "memory");

    // ---- epilogue: bias + store ----
    #pragma unroll
    for (int m = 0; m < 8; ++m) {
        #pragma unroll
        for (int n = 0; n < 4; ++n) {
            int col = bn + wc * 64 + n * 16 + fr;
            float bv = bias[col];
            #pragma unroll
            for (int r = 0; r < 4; ++r) {
                int row = bm + wr * 128 + m * 16 + fq * 4 + r;
                float v = acc[m][n][r] + bv;
                if (OUT_BF16)
                    ((unsigned short*)Cout)[(size_t)row * N + col] = f2bf(v);
                else
                    ((float*)Cout)[(size_t)row * N + col] = v;
            }
        }
    }
}

// ---------------- per-position head-mixing attention (MFMA QK^T) ----------------
__global__ __launch_bounds__(64)
void attn_kernel(const unsigned short* __restrict__ qkv,
                 unsigned short* __restrict__ out) {
    __shared__ float sv[16][68];   // row stride 272B: 16B-aligned for float4
    __shared__ float sp[16][17];
    int pos = blockIdx.x;
    int l = threadIdx.x;
    const unsigned short* rowp = qkv + (size_t)pos * 3072;

    #pragma unroll
    for (int j = 0; j < 4; ++j) {
        int i8 = (j * 64 + l) * 8;
        int h = i8 >> 6, d = i8 & 63;
        ushort4 v0 = *reinterpret_cast<const ushort4*>(rowp + h * 192 + 128 + d);
        ushort4 v1 = *reinterpret_cast<const ushort4*>(rowp + h * 192 + 128 + d + 4);
        sv[h][d + 0] = bf2f(v0.x); sv[h][d + 1] = bf2f(v0.y);
        sv[h][d + 2] = bf2f(v0.z); sv[h][d + 3] = bf2f(v0.w);
        sv[h][d + 4] = bf2f(v1.x); sv[h][d + 5] = bf2f(v1.y);
        sv[h][d + 6] = bf2f(v1.z); sv[h][d + 7] = bf2f(v1.w);
    }

    int fr = l & 15, fq = l >> 4;
    const unsigned short* hb = rowp + fr * 192 + fq * 8;
    bf16x8 kf0 = *reinterpret_cast<const bf16x8*>(hb + 64);
    bf16x8 kf1 = *reinterpret_cast<const bf16x8*>(hb + 96);
    bf16x8 qf0 = *reinterpret_cast<const bf16x8*>(hb);
    bf16x8 qf1 = *reinterpret_cast<const bf16x8*>(hb + 32);
    f32x4 st = {};
    st = __builtin_amdgcn_mfma_f32_16x16x32_bf16(kf0, qf0, st, 0, 0, 0);
    st = __builtin_amdgcn_mfma_f32_16x16x32_bf16(kf1, qf1, st, 0, 0, 0);

    float s0 = st[0] * 0.03125f, s1 = st[1] * 0.03125f;
    float s2 = st[2] * 0.03125f, s3 = st[3] * 0.03125f;
    float m = fmaxf(fmaxf(s0, s1), fmaxf(s2, s3));
    m = fmaxf(m, __shfl_xor(m, 16));
    m = fmaxf(m, __shfl_xor(m, 32));
    float e0 = __expf(s0 - m), e1 = __expf(s1 - m);
    float e2 = __expf(s2 - m), e3 = __expf(s3 - m);
    float sum = e0 + e1 + e2 + e3;
    sum += __shfl_xor(sum, 16);
    sum += __shfl_xor(sum, 32);
    float inv = 1.0f / sum;
    sp[fr][fq * 4 + 0] = e0 * inv;
    sp[fr][fq * 4 + 1] = e1 * inv;
    sp[fr][fq * 4 + 2] = e2 * inv;
    sp[fr][fq * 4 + 3] = e3 * inv;
    __syncthreads();

    int h2 = l >> 2, tq = l & 3;
    int dbase = tq * 16;
    float4 o0 = {}, o1 = {}, o2 = {}, o3 = {};
    #pragma unroll
    for (int tt = 0; tt < 16; ++tt) {
        float p = sp[h2][tt];
        float4 v0 = *reinterpret_cast<const float4*>(&sv[tt][dbase + 0]);
        float4 v1 = *reinterpret_cast<const float4*>(&sv[tt][dbase + 4]);
        float4 v2 = *reinterpret_cast<const float4*>(&sv[tt][dbase + 8]);
        float4 v3 = *reinterpret_cast<const float4*>(&sv[tt][dbase + 12]);
        o0.x += p * v0.x; o0.y += p * v0.y; o0.z += p * v0.z; o0.w += p * v0.w;
        o1.x += p * v1.x; o1.y += p * v1.y; o1.z += p * v1.z; o1.w += p * v1.w;
        o2.x += p * v2.x; o2.y += p * v2.y; o2.z += p * v2.z; o2.w += p * v2.w;
        o3.x += p * v3.x; o3.y += p * v3.y; o3.z += p * v3.z; o3.w += p * v3.w;
    }
    ushort4* po = (ushort4*)(out + (size_t)pos * 1024 + h2 * 64 + dbase);
    ushort4 w0 = { f2bf(o0.x), f2bf(o0.y), f2bf(o0.z), f2bf(o0.w) };
    ushort4 w1 = { f2bf(o1.x), f2bf(o1.y), f2bf(o1.z), f2bf(o1.w) };
    ushort4 w2 = { f2bf(o2.x), f2bf(o2.y), f2bf(o2.z), f2bf(o2.w) };
    ushort4 w3 = { f2bf(o3.x), f2bf(o3.y), f2bf(o3.z), f2bf(o3.w) };
    po[0] = w0; po[1] = w1; po[2] = w2; po[3] = w3;
}

extern "C" void kernel_launch(void* const* d_in, const int* in_sizes, int n_in,
                              void* d_out, int out_size, void* d_ws, size_t ws_size,
                              hipStream_t stream) {
    const float* x     = (const float*)d_in[0];
    const float* w_qkv = (const float*)d_in[1];
    const float* b_qkv = (const float*)d_in[2];
    const float* w_o   = (const float*)d_in[3];
    const float* b_o   = (const float*)d_in[4];
    float* out = (float*)d_out;

    const int C = 1024, E = 1024;
    const int M = 16 * 1024;      // B*S = 16384
    const int N1 = 3 * E;         // 3072

    char* ws = (char*)d_ws;
    unsigned short* xb    = (unsigned short*)ws;            // M*C bf16
    unsigned short* wqkvT = xb    + (size_t)M * C;          // N1*C
    unsigned short* qkv   = wqkvT + (size_t)N1 * C;         // M*N1
    unsigned short* woT   = qkv   + (size_t)M * N1;         // E*E
    unsigned short* aout  = woT   + (size_t)E * E;          // M*E

    cvt_f32_bf16<<<2048, 256, 0, stream>>>(x, xb, M * C);
    dim3 tb(32, 8);
    transpose_cvt<<<dim3(N1 / 32, C / 32), tb, 0, stream>>>(w_qkv, wqkvT, C, N1);
    transpose_cvt<<<dim3(E / 32, E / 32), tb, 0, stream>>>(w_o, woT, E, E);

    // QKV: M=16384, N=3072, K=1024 -> 768 blocks
    gemm256<true><<<dim3((M / 256) * (N1 / 256)), 512, 0, stream>>>(
        xb, wqkvT, b_qkv, qkv, M, N1, C, N1 / 256);
    attn_kernel<<<M, 64, 0, stream>>>(qkv, aout);
    // O-proj: M=16384, N=1024 -> 256 blocks
    gemm256<false><<<dim3((M / 256) * (E / 256)), 512, 0, stream>>>(
        aout, woT, b_o, out, M, E, E, E / 256);
}

// Round 9
// 203.833 us; speedup vs baseline: 1.3108x; 1.3108x over previous
//
#include <hip/hip_runtime.h>
#include <hip/hip_bf16.h>
#include <stdint.h>

#define DEVINLINE __device__ __forceinline__

typedef __attribute__((ext_vector_type(4))) float f32x4;
typedef __attribute__((ext_vector_type(16))) float f32x16;
typedef __attribute__((ext_vector_type(8))) short bf16x8;

DEVINLINE unsigned short f2bf(float f) {
    union { float f; uint32_t u; } v; v.f = f;
    uint32_t u = v.u;
    uint32_t rounding = 0x7FFFu + ((u >> 16) & 1u);
    u += rounding;
    return (unsigned short)(u >> 16);
}

DEVINLINE float bf2f(unsigned short h) {
    union { uint32_t u; float f; } v; v.u = ((uint32_t)h) << 16;
    return v.f;
}

// ---------------- fp32 -> bf16 elementwise convert ----------------
__global__ void cvt_f32_bf16(const float* __restrict__ in,
                             unsigned short* __restrict__ out, int n) {
    int i = (blockIdx.x * blockDim.x + threadIdx.x) * 4;
    int stride = gridDim.x * blockDim.x * 4;
    for (; i < n; i += stride) {
        float4 v = *reinterpret_cast<const float4*>(in + i);
        ushort4 o;
        o.x = f2bf(v.x); o.y = f2bf(v.y); o.z = f2bf(v.z); o.w = f2bf(v.w);
        *reinterpret_cast<ushort4*>(out + i) = o;
    }
}

// ---------------- fp32 [R][C] -> bf16 [C][R] transpose ----------------
__global__ void transpose_cvt(const float* __restrict__ in,
                              unsigned short* __restrict__ out,
                              int R, int Ccols) {
    __shared__ float tile[32][33];
    int c0 = blockIdx.x * 32, r0 = blockIdx.y * 32;
    int tx = threadIdx.x, ty = threadIdx.y; // 32 x 8
    #pragma unroll
    for (int j = 0; j < 32; j += 8)
        tile[ty + j][tx] = in[(size_t)(r0 + ty + j) * Ccols + c0 + tx];
    __syncthreads();
    #pragma unroll
    for (int j = 0; j < 32; j += 8)
        out[(size_t)(c0 + ty + j) * R + r0 + tx] = f2bf(tile[tx][ty + j]);
}

// ============ 256x256 bf16 GEMM, R5 schedule + 32x32x16 MFMA ============
// 8 waves (2M x 4N), BK=64, 128 KiB LDS double-buffered (A + B^T, XOR-swizzled).
// Phase p = { MMA(quadrant p); ds_reads for phase p+1; [stages]; [vmcnt]; s_barrier }.
// Quadrants (0,0),(0,1),(1,0),(1,1); reads 4/8/4/8 b128; stages B(t+2)@p2, A(t+2)@p3.
// 32x32x16 fragments: rl=lane&31 (row), hi=lane>>5, k=hi*8+j; slot=(ks*2+hi)^(rl&7).
// C/D: col=lane&31, row=(reg&3)+8*(reg>>2)+4*hi  [m74/m101 verified].

#define GLD(srcp, dstp) __builtin_amdgcn_global_load_lds( \
    (const __attribute__((address_space(1))) void*)(srcp), \
    (__attribute__((address_space(3))) void*)(dstp), 16, 0, 0)

// stage one half-tile (128 rows x 64 cols bf16): 2 loads x 8 waves
#define STAGE(P, regionUS, srcBase, row0, kkE) do { \
    const unsigned short* _s = (srcBase) + (size_t)(row0) * K + (kkE); \
    unsigned short* _d = lds + (P) * 32768 + (regionUS) + wid * 512; \
    GLD(_s, _d); GLD(_s + (size_t)64 * K, _d + 4096); } while (0)

// A m-half h (64 rows): 2 mb x 4 ks = 8 b128
#define RD_A(dst, Ab, h) do { \
    dst[0][0] = *(const bf16x8*)((Ab) + (h) * 8192 + cS0); \
    dst[0][1] = *(const bf16x8*)((Ab) + (h) * 8192 + cS1); \
    dst[0][2] = *(const bf16x8*)((Ab) + (h) * 8192 + cS2); \
    dst[0][3] = *(const bf16x8*)((Ab) + (h) * 8192 + cS3); \
    dst[1][0] = *(const bf16x8*)((Ab) + (h) * 8192 + 4096 + cS0); \
    dst[1][1] = *(const bf16x8*)((Ab) + (h) * 8192 + 4096 + cS1); \
    dst[1][2] = *(const bf16x8*)((Ab) + (h) * 8192 + 4096 + cS2); \
    dst[1][3] = *(const bf16x8*)((Ab) + (h) * 8192 + 4096 + cS3); } while (0)

// B n-half nh (32 cols): 4 ks = 4 b128
#define RD_B(dst, Bb, nh) do { \
    dst[0] = *(const bf16x8*)((Bb) + (nh) * 4096 + cS0); \
    dst[1] = *(const bf16x8*)((Bb) + (nh) * 4096 + cS1); \
    dst[2] = *(const bf16x8*)((Bb) + (nh) * 4096 + cS2); \
    dst[3] = *(const bf16x8*)((Bb) + (nh) * 4096 + cS3); } while (0)

// 8 x mfma_32x32x16 per quadrant (2 independent acc chains interleaved)
#define MMA(aX, bY, mh, nh) do { \
    __builtin_amdgcn_s_setprio(1); \
    _Pragma("unroll") for (int _k = 0; _k < 4; ++_k) { \
    _Pragma("unroll") for (int _m = 0; _m < 2; ++_m) { \
        acc[(mh)*2+_m][(nh)] = __builtin_amdgcn_mfma_f32_32x32x16_bf16( \
            aX[_m][_k], bY[_k], acc[(mh)*2+_m][(nh)], 0, 0, 0); } } \
    __builtin_amdgcn_s_setprio(0); } while (0)

#define VM4 asm volatile("s_waitcnt vmcnt(4)" ::: "memory")
#define BAR() asm volatile("s_barrier" ::: "memory")

// One K-tile (R5 schedule), parity-static LDS bases. kk = clamped stage col.
#define KTILE(Abc, Bbc, Abn, Bbn, Pc, kk) do { \
    MMA(aA, bA, 0, 0); \
    RD_B(bB, Bbc, 1); \
    BAR(); \
    MMA(aA, bB, 0, 1); \
    RD_A(aB, Abc, 1); \
    VM4; BAR(); \
    MMA(aB, bA, 1, 0); \
    RD_B(bA, Bbn, 0); \
    STAGE(Pc, 16384, bSrc, 0,   kk); \
    STAGE(Pc, 24576, bSrc, 128, kk); \
    VM4; BAR(); \
    MMA(aB, bB, 1, 1); \
    RD_A(aA, Abn, 0); \
    STAGE(Pc, 0,     aSrc, 0,   kk); \
    STAGE(Pc, 8192,  aSrc, 128, kk); \
    BAR(); } while (0)

template <bool OUT_BF16>
__launch_bounds__(512, 2)
__global__ void gemm256(const unsigned short* __restrict__ A,
                        const unsigned short* __restrict__ Bt,
                        const float* __restrict__ bias,
                        void* __restrict__ Cout,
                        int M, int N, int K, int NTN) {
    __shared__ unsigned short lds[65536]; // 128 KiB: 2 buf x (A 256x64 + B 256x64)
    const int NT = K >> 6;                // K-tiles (even, >= 2)

    int t = threadIdx.x;
    int wid = t >> 6, lane = t & 63;
    int wr = wid >> 2, wc = wid & 3;
    int rl = lane & 31, hi = lane >> 5;

    // XCD-aware block swizzle (grid % 8 == 0)
    int nwg = gridDim.x, bid = blockIdx.x;
    int cpx = nwg >> 3;
    int swz = (bid & 7) * cpx + (bid >> 3);
    int tm = swz / NTN, tn = swz % NTN;
    int bm = tm * 256, bn = tn * 256;

    // staging source (per-lane, pre-swizzled 16B slot)
    int rowl = t >> 3, col8 = t & 7;
    int swzcol = (col8 ^ (rowl & 7)) << 3;
    const unsigned short* aSrc = A + (size_t)(bm + rowl) * K + swzcol;
    const unsigned short* bSrc = Bt + (size_t)(bn + rowl) * K + swzcol;

    // ds_read swizzled byte offsets for ks=0..3: slot=(ks*2+hi)^(rl&7), 16B each
    int sm = rl & 7;
    int cS0 = ((0 * 2 + hi) ^ sm) << 4;
    int cS1 = ((1 * 2 + hi) ^ sm) << 4;
    int cS2 = ((2 * 2 + hi) ^ sm) << 4;
    int cS3 = ((3 * 2 + hi) ^ sm) << 4;

    char* ldsb = (char*)lds;
    char* A0 = ldsb + ((wr * 128 + rl) << 7);          // parity 0, m-half offset added at read
    char* B0 = ldsb + ((256 + wc * 64 + rl) << 7);
    char* A1 = A0 + 65536;
    char* B1 = B0 + 65536;

    f32x16 acc[4][2] = {};
    bf16x8 aA[2][4], aB[2][4], bA[4], bB[4];

    // ---- prologue: 16 loads = tiles 0 and 1, order A(0),B(0),B(1),A(1) ----
    STAGE(0, 0,     aSrc, 0,   0);   // A0(0)
    STAGE(0, 8192,  aSrc, 128, 0);   // A1(0)
    STAGE(0, 16384, bSrc, 0,   0);   // B0(0)
    STAGE(0, 24576, bSrc, 128, 0);   // B1(0)
    STAGE(1, 16384, bSrc, 0,   64);  // B0(1)
    STAGE(1, 24576, bSrc, 128, 64);  // B1(1)
    STAGE(1, 0,     aSrc, 0,   64);  // A0(1)
    STAGE(1, 8192,  aSrc, 128, 64);  // A1(1)
    asm volatile("s_waitcnt vmcnt(8)" ::: "memory"); // A(0),B(0) landed
    BAR();
    RD_A(aA, A0, 0);
    RD_B(bA, B0, 0);

    for (int tau = 0; tau < NT; tau += 2) {
        int kkA = ((tau + 2 < NT) ? (tau + 2) : (NT - 1)) << 6;
        KTILE(A0, B0, A1, B1, 0, kkA);
        int kkB = ((tau + 3 < NT) ? (tau + 3) : (NT - 1)) << 6;
        KTILE(A1, B1, A0, B0, 1, kkB);
    }
    asm volatile("s_waitcnt vmcnt(0)" ::: "memory");

    // ---- epilogue: bias + store (32x32 C/D layout) ----
    #pragma unroll
    for (int mq = 0; mq < 4; ++mq) {
        #pragma unroll
        for (int nh = 0; nh < 2; ++nh) {
            int col = bn + wc * 64 + nh * 32 + rl;
            float bv = bias[col];
            #pragma unroll
            for (int r = 0; r < 16; ++r) {
                int row = bm + wr * 128 + mq * 32 + (r & 3) + 8 * (r >> 2) + 4 * hi;
                float v = acc[mq][nh][r] + bv;
                if (OUT_BF16)
                    ((unsigned short*)Cout)[(size_t)row * N + col] = f2bf(v);
                else
                    ((float*)Cout)[(size_t)row * N + col] = v;
            }
        }
    }
}

// ---------------- per-position head-mixing attention (MFMA QK^T) ----------------
__global__ __launch_bounds__(64)
void attn_kernel(const unsigned short* __restrict__ qkv,
                 unsigned short* __restrict__ out) {
    __shared__ float sv[16][68];   // row stride 272B: 16B-aligned for float4
    __shared__ float sp[16][17];
    int pos = blockIdx.x;
    int l = threadIdx.x;
    const unsigned short* rowp = qkv + (size_t)pos * 3072;

    #pragma unroll
    for (int j = 0; j < 4; ++j) {
        int i8 = (j * 64 + l) * 8;
        int h = i8 >> 6, d = i8 & 63;
        ushort4 v0 = *reinterpret_cast<const ushort4*>(rowp + h * 192 + 128 + d);
        ushort4 v1 = *reinterpret_cast<const ushort4*>(rowp + h * 192 + 128 + d + 4);
        sv[h][d + 0] = bf2f(v0.x); sv[h][d + 1] = bf2f(v0.y);
        sv[h][d + 2] = bf2f(v0.z); sv[h][d + 3] = bf2f(v0.w);
        sv[h][d + 4] = bf2f(v1.x); sv[h][d + 5] = bf2f(v1.y);
        sv[h][d + 6] = bf2f(v1.z); sv[h][d + 7] = bf2f(v1.w);
    }

    int fr = l & 15, fq = l >> 4;
    const unsigned short* hb = rowp + fr * 192 + fq * 8;
    bf16x8 kf0 = *reinterpret_cast<const bf16x8*>(hb + 64);
    bf16x8 kf1 = *reinterpret_cast<const bf16x8*>(hb + 96);
    bf16x8 qf0 = *reinterpret_cast<const bf16x8*>(hb);
    bf16x8 qf1 = *reinterpret_cast<const bf16x8*>(hb + 32);
    f32x4 st = {};
    st = __builtin_amdgcn_mfma_f32_16x16x32_bf16(kf0, qf0, st, 0, 0, 0);
    st = __builtin_amdgcn_mfma_f32_16x16x32_bf16(kf1, qf1, st, 0, 0, 0);

    float s0 = st[0] * 0.03125f, s1 = st[1] * 0.03125f;
    float s2 = st[2] * 0.03125f, s3 = st[3] * 0.03125f;
    float m = fmaxf(fmaxf(s0, s1), fmaxf(s2, s3));
    m = fmaxf(m, __shfl_xor(m, 16));
    m = fmaxf(m, __shfl_xor(m, 32));
    float e0 = __expf(s0 - m), e1 = __expf(s1 - m);
    float e2 = __expf(s2 - m), e3 = __expf(s3 - m);
    float sum = e0 + e1 + e2 + e3;
    sum += __shfl_xor(sum, 16);
    sum += __shfl_xor(sum, 32);
    float inv = 1.0f / sum;
    sp[fr][fq * 4 + 0] = e0 * inv;
    sp[fr][fq * 4 + 1] = e1 * inv;
    sp[fr][fq * 4 + 2] = e2 * inv;
    sp[fr][fq * 4 + 3] = e3 * inv;
    __syncthreads();

    int h2 = l >> 2, tq = l & 3;
    int dbase = tq * 16;
    float4 o0 = {}, o1 = {}, o2 = {}, o3 = {};
    #pragma unroll
    for (int tt = 0; tt < 16; ++tt) {
        float p = sp[h2][tt];
        float4 v0 = *reinterpret_cast<const float4*>(&sv[tt][dbase + 0]);
        float4 v1 = *reinterpret_cast<const float4*>(&sv[tt][dbase + 4]);
        float4 v2 = *reinterpret_cast<const float4*>(&sv[tt][dbase + 8]);
        float4 v3 = *reinterpret_cast<const float4*>(&sv[tt][dbase + 12]);
        o0.x += p * v0.x; o0.y += p * v0.y; o0.z += p * v0.z; o0.w += p * v0.w;
        o1.x += p * v1.x; o1.y += p * v1.y; o1.z += p * v1.z; o1.w += p * v1.w;
        o2.x += p * v2.x; o2.y += p * v2.y; o2.z += p * v2.z; o2.w += p * v2.w;
        o3.x += p * v3.x; o3.y += p * v3.y; o3.z += p * v3.z; o3.w += p * v3.w;
    }
    ushort4* po = (ushort4*)(out + (size_t)pos * 1024 + h2 * 64 + dbase);
    ushort4 w0 = { f2bf(o0.x), f2bf(o0.y), f2bf(o0.z), f2bf(o0.w) };
    ushort4 w1 = { f2bf(o1.x), f2bf(o1.y), f2bf(o1.z), f2bf(o1.w) };
    ushort4 w2 = { f2bf(o2.x), f2bf(o2.y), f2bf(o2.z), f2bf(o2.w) };
    ushort4 w3 = { f2bf(o3.x), f2bf(o3.y), f2bf(o3.z), f2bf(o3.w) };
    po[0] = w0; po[1] = w1; po[2] = w2; po[3] = w3;
}

extern "C" void kernel_launch(void* const* d_in, const int* in_sizes, int n_in,
                              void* d_out, int out_size, void* d_ws, size_t ws_size,
                              hipStream_t stream) {
    const float* x     = (const float*)d_in[0];
    const float* w_qkv = (const float*)d_in[1];
    const float* b_qkv = (const float*)d_in[2];
    const float* w_o   = (const float*)d_in[3];
    const float* b_o   = (const float*)d_in[4];
    float* out = (float*)d_out;

    const int C = 1024, E = 1024;
    const int M = 16 * 1024;      // B*S = 16384
    const int N1 = 3 * E;         // 3072

    char* ws = (char*)d_ws;
    unsigned short* xb    = (unsigned short*)ws;            // M*C bf16
    unsigned short* wqkvT = xb    + (size_t)M * C;          // N1*C
    unsigned short* qkv   = wqkvT + (size_t)N1 * C;         // M*N1
    unsigned short* woT   = qkv   + (size_t)M * N1;         // E*E
    unsigned short* aout  = woT   + (size_t)E * E;          // M*E

    cvt_f32_bf16<<<2048, 256, 0, stream>>>(x, xb, M * C);
    dim3 tb(32, 8);
    transpose_cvt<<<dim3(N1 / 32, C / 32), tb, 0, stream>>>(w_qkv, wqkvT, C, N1);
    transpose_cvt<<<dim3(E / 32, E / 32), tb, 0, stream>>>(w_o, woT, E, E);

    // QKV: M=16384, N=3072, K=1024 -> 768 blocks
    gemm256<true><<<dim3((M / 256) * (N1 / 256)), 512, 0, stream>>>(
        xb, wqkvT, b_qkv, qkv, M, N1, C, N1 / 256);
    attn_kernel<<<M, 64, 0, stream>>>(qkv, aout);
    // O-proj: M=16384, N=1024 -> 256 blocks
    gemm256<false><<<dim3((M / 256) * (E / 256)), 512, 0, stream>>>(
        aout, woT, b_o, out, M, E, E, E / 256);
}

// Round 10
// 196.059 us; speedup vs baseline: 1.3628x; 1.0397x over previous
//
#include <hip/hip_runtime.h>
#include <hip/hip_bf16.h>
#include <stdint.h>

#define DEVINLINE __device__ __forceinline__

typedef __attribute__((ext_vector_type(4))) float f32x4;
typedef __attribute__((ext_vector_type(8))) short bf16x8;

DEVINLINE unsigned short f2bf(float f) {
    union { float f; uint32_t u; } v; v.f = f;
    uint32_t u = v.u;
    uint32_t rounding = 0x7FFFu + ((u >> 16) & 1u);
    u += rounding;
    return (unsigned short)(u >> 16);
}

DEVINLINE float bf2f(unsigned short h) {
    union { uint32_t u; float f; } v; v.u = ((uint32_t)h) << 16;
    return v.f;
}

// ---------------- fp32 -> bf16 elementwise convert ----------------
__global__ void cvt_f32_bf16(const float* __restrict__ in,
                             unsigned short* __restrict__ out, int n) {
    int i = (blockIdx.x * blockDim.x + threadIdx.x) * 4;
    int stride = gridDim.x * blockDim.x * 4;
    for (; i < n; i += stride) {
        float4 v = *reinterpret_cast<const float4*>(in + i);
        ushort4 o;
        o.x = f2bf(v.x); o.y = f2bf(v.y); o.z = f2bf(v.z); o.w = f2bf(v.w);
        *reinterpret_cast<ushort4*>(out + i) = o;
    }
}

// ---------------- fp32 [R][C] -> bf16 [C][R] transpose ----------------
__global__ void transpose_cvt(const float* __restrict__ in,
                              unsigned short* __restrict__ out,
                              int R, int Ccols) {
    __shared__ float tile[32][33];
    int c0 = blockIdx.x * 32, r0 = blockIdx.y * 32;
    int tx = threadIdx.x, ty = threadIdx.y; // 32 x 8
    #pragma unroll
    for (int j = 0; j < 32; j += 8)
        tile[ty + j][tx] = in[(size_t)(r0 + ty + j) * Ccols + c0 + tx];
    __syncthreads();
    #pragma unroll
    for (int j = 0; j < 32; j += 8)
        out[(size_t)(c0 + ty + j) * R + r0 + tx] = f2bf(tile[tx][ty + j]);
}

// ============ 256x256 bf16 GEMM, R5 schedule with reads-before-MMA ============
// 8 waves (2M x 4N), BK=64, 128 KiB LDS double-buffered, 16x16x32 MFMA.
// Phase p = { ds_reads(p+1) + stages FIRST; then MMA(quadrant p); [vmcnt]; BAR }.
// Reads before the setprio-fenced MFMA window let the compiler emit counted
// lgkmcnt -> LDS pipe drains concurrently with the MFMA pipe.
// bA is register-double-buffered (bAe/bAo) to break the p2 WAR hazard.

#define GLD(srcp, dstp) __builtin_amdgcn_global_load_lds( \
    (const __attribute__((address_space(1))) void*)(srcp), \
    (__attribute__((address_space(3))) void*)(dstp), 16, 0, 0)

// stage one half-tile (128 rows x 64 cols bf16): 2 loads x 8 waves
#define STAGE(P, regionUS, srcBase, row0, kkE) do { \
    const unsigned short* _s = (srcBase) + (size_t)(row0) * K + (kkE); \
    unsigned short* _d = lds + (P) * 32768 + (regionUS) + wid * 512; \
    GLD(_s, _d); GLD(_s + (size_t)64 * K, _d + 4096); } while (0)

#define RD_A(dst, AS0, AS1, h) do { _Pragma("unroll") \
    for (int _i = 0; _i < 4; ++_i) { \
        dst[_i][0] = *(const bf16x8*)((AS0) + ((h) * 8192 + _i * 2048)); \
        dst[_i][1] = *(const bf16x8*)((AS1) + ((h) * 8192 + _i * 2048)); } } while (0)

#define RD_B(dst, BS0, BS1, nh) do { _Pragma("unroll") \
    for (int _j = 0; _j < 2; ++_j) { \
        dst[_j][0] = *(const bf16x8*)((BS0) + ((nh) * 4096 + _j * 2048)); \
        dst[_j][1] = *(const bf16x8*)((BS1) + ((nh) * 4096 + _j * 2048)); } } while (0)

#define MMA(aX, bY, mh, nh) do { \
    __builtin_amdgcn_s_setprio(1); \
    _Pragma("unroll") for (int _i = 0; _i < 4; ++_i) { \
    _Pragma("unroll") for (int _j = 0; _j < 2; ++_j) { \
        acc[(mh)*4+_i][(nh)*2+_j] = __builtin_amdgcn_mfma_f32_16x16x32_bf16( \
            aX[_i][0], bY[_j][0], acc[(mh)*4+_i][(nh)*2+_j], 0, 0, 0); \
        acc[(mh)*4+_i][(nh)*2+_j] = __builtin_amdgcn_mfma_f32_16x16x32_bf16( \
            aX[_i][1], bY[_j][1], acc[(mh)*4+_i][(nh)*2+_j], 0, 0, 0); } } \
    __builtin_amdgcn_s_setprio(0); } while (0)

#define VM4 asm volatile("s_waitcnt vmcnt(4)" ::: "memory")
#define BAR() asm volatile("s_barrier" ::: "memory")

// One K-tile (R5 ledger; intra-phase: reads/stages first, MMA last).
// bAc = bA regs for this tile; bAn = bA regs being filled for next tile.
#define KTILE(AS0c, AS1c, BS0c, BS1c, AS0n, AS1n, BS0n, BS1n, Pc, kk, bAc, bAn) do { \
    RD_B(bB, BS0c, BS1c, 1); \
    MMA(aA, bAc, 0, 0); \
    BAR(); \
    RD_A(aB, AS0c, AS1c, 1); \
    MMA(aA, bB, 0, 1); \
    VM4; BAR(); \
    RD_B(bAn, BS0n, BS1n, 0); \
    STAGE(Pc, 16384, bSrc, 0,   kk); \
    STAGE(Pc, 24576, bSrc, 128, kk); \
    MMA(aB, bAc, 1, 0); \
    VM4; BAR(); \
    RD_A(aA, AS0n, AS1n, 0); \
    STAGE(Pc, 0,     aSrc, 0,   kk); \
    STAGE(Pc, 8192,  aSrc, 128, kk); \
    MMA(aB, bB, 1, 1); \
    BAR(); } while (0)

template <bool OUT_BF16>
__launch_bounds__(512, 2)
__global__ void gemm256(const unsigned short* __restrict__ A,
                        const unsigned short* __restrict__ Bt,
                        const float* __restrict__ bias,
                        void* __restrict__ Cout,
                        int M, int N, int K, int NTN) {
    __shared__ unsigned short lds[65536]; // 128 KiB: 2 buf x (A 256x64 + B 256x64)
    const int NT = K >> 6;                // K-tiles (even, >= 2)

    int t = threadIdx.x;
    int wid = t >> 6, lane = t & 63;
    int wr = wid >> 2, wc = wid & 3;
    int fr = lane & 15, fq = lane >> 4;

    // XCD-aware block swizzle (grid % 8 == 0)
    int nwg = gridDim.x, bid = blockIdx.x;
    int cpx = nwg >> 3;
    int swz = (bid & 7) * cpx + (bid >> 3);
    int tm = swz / NTN, tn = swz % NTN;
    int bm = tm * 256, bn = tn * 256;

    // staging source (per-lane, pre-swizzled 16B slot)
    int rowl = t >> 3, col8 = t & 7;
    int swzcol = (col8 ^ (rowl & 7)) << 3;
    const unsigned short* aSrc = A + (size_t)(bm + rowl) * K + swzcol;
    const unsigned short* bSrc = Bt + (size_t)(bn + rowl) * K + swzcol;

    // ds_read swizzled base pointers (row&7 == fr&7 for all fragment rows)
    int swzm = (fr & 7) << 3;
    int colS0 = (fq << 3) ^ swzm;
    int colS1 = (32 | (fq << 3)) ^ swzm;

    char* ldsb = (char*)lds;
    char* A00 = ldsb + ((wr * 128 + fr) << 7) + 2 * colS0;
    char* A10 = ldsb + ((wr * 128 + fr) << 7) + 2 * colS1;
    char* B00 = ldsb + ((256 + wc * 64 + fr) << 7) + 2 * colS0;
    char* B10 = ldsb + ((256 + wc * 64 + fr) << 7) + 2 * colS1;
    char* A01 = A00 + 65536; char* A11 = A10 + 65536;
    char* B01 = B00 + 65536; char* B11 = B10 + 65536;

    f32x4 acc[8][4] = {};
    bf16x8 aA[4][2], aB[4][2], bAe[2][2], bAo[2][2], bB[2][2];

    // ---- prologue: 16 loads = tiles 0 and 1, order A(0),B(0),B(1),A(1) ----
    STAGE(0, 0,     aSrc, 0,   0);   // A0(0)
    STAGE(0, 8192,  aSrc, 128, 0);   // A1(0)
    STAGE(0, 16384, bSrc, 0,   0);   // B0(0)
    STAGE(0, 24576, bSrc, 128, 0);   // B1(0)
    STAGE(1, 16384, bSrc, 0,   64);  // B0(1)
    STAGE(1, 24576, bSrc, 128, 64);  // B1(1)
    STAGE(1, 0,     aSrc, 0,   64);  // A0(1)
    STAGE(1, 8192,  aSrc, 128, 64);  // A1(1)
    asm volatile("s_waitcnt vmcnt(8)" ::: "memory"); // A(0),B(0) landed
    BAR();
    RD_A(aA, A00, A10, 0);    // A(0) h=0
    RD_B(bAe, B00, B10, 0);   // B(0) nh=0

    for (int tau = 0; tau < NT; tau += 2) {
        int kkA = ((tau + 2 < NT) ? (tau + 2) : (NT - 1)) << 6;
        KTILE(A00, A10, B00, B10, A01, A11, B01, B11, 0, kkA, bAe, bAo);
        int kkB = ((tau + 3 < NT) ? (tau + 3) : (NT - 1)) << 6;
        KTILE(A01, A11, B01, B11, A00, A10, B00, B10, 1, kkB, bAo, bAe);
    }
    asm volatile("s_waitcnt vmcnt(0)" ::: "memory");

    // ---- epilogue: bias + store ----
    #pragma unroll
    for (int m = 0; m < 8; ++m) {
        #pragma unroll
        for (int n = 0; n < 4; ++n) {
            int col = bn + wc * 64 + n * 16 + fr;
            float bv = bias[col];
            #pragma unroll
            for (int r = 0; r < 4; ++r) {
                int row = bm + wr * 128 + m * 16 + fq * 4 + r;
                float v = acc[m][n][r] + bv;
                if (OUT_BF16)
                    ((unsigned short*)Cout)[(size_t)row * N + col] = f2bf(v);
                else
                    ((float*)Cout)[(size_t)row * N + col] = v;
            }
        }
    }
}

// ---------------- per-position head-mixing attention (MFMA QK^T) ----------------
__global__ __launch_bounds__(64)
void attn_kernel(const unsigned short* __restrict__ qkv,
                 unsigned short* __restrict__ out) {
    __shared__ float sv[16][68];   // row stride 272B: 16B-aligned for float4
    __shared__ float sp[16][17];
    int pos = blockIdx.x;
    int l = threadIdx.x;
    const unsigned short* rowp = qkv + (size_t)pos * 3072;

    #pragma unroll
    for (int j = 0; j < 4; ++j) {
        int i8 = (j * 64 + l) * 8;
        int h = i8 >> 6, d = i8 & 63;
        ushort4 v0 = *reinterpret_cast<const ushort4*>(rowp + h * 192 + 128 + d);
        ushort4 v1 = *reinterpret_cast<const ushort4*>(rowp + h * 192 + 128 + d + 4);
        sv[h][d + 0] = bf2f(v0.x); sv[h][d + 1] = bf2f(v0.y);
        sv[h][d + 2] = bf2f(v0.z); sv[h][d + 3] = bf2f(v0.w);
        sv[h][d + 4] = bf2f(v1.x); sv[h][d + 5] = bf2f(v1.y);
        sv[h][d + 6] = bf2f(v1.z); sv[h][d + 7] = bf2f(v1.w);
    }

    int fr = l & 15, fq = l >> 4;
    const unsigned short* hb = rowp + fr * 192 + fq * 8;
    bf16x8 kf0 = *reinterpret_cast<const bf16x8*>(hb + 64);
    bf16x8 kf1 = *reinterpret_cast<const bf16x8*>(hb + 96);
    bf16x8 qf0 = *reinterpret_cast<const bf16x8*>(hb);
    bf16x8 qf1 = *reinterpret_cast<const bf16x8*>(hb + 32);
    f32x4 st = {};
    st = __builtin_amdgcn_mfma_f32_16x16x32_bf16(kf0, qf0, st, 0, 0, 0);
    st = __builtin_amdgcn_mfma_f32_16x16x32_bf16(kf1, qf1, st, 0, 0, 0);

    float s0 = st[0] * 0.03125f, s1 = st[1] * 0.03125f;
    float s2 = st[2] * 0.03125f, s3 = st[3] * 0.03125f;
    float m = fmaxf(fmaxf(s0, s1), fmaxf(s2, s3));
    m = fmaxf(m, __shfl_xor(m, 16));
    m = fmaxf(m, __shfl_xor(m, 32));
    float e0 = __expf(s0 - m), e1 = __expf(s1 - m);
    float e2 = __expf(s2 - m), e3 = __expf(s3 - m);
    float sum = e0 + e1 + e2 + e3;
    sum += __shfl_xor(sum, 16);
    sum += __shfl_xor(sum, 32);
    float inv = 1.0f / sum;
    sp[fr][fq * 4 + 0] = e0 * inv;
    sp[fr][fq * 4 + 1] = e1 * inv;
    sp[fr][fq * 4 + 2] = e2 * inv;
    sp[fr][fq * 4 + 3] = e3 * inv;
    __syncthreads();

    int h2 = l >> 2, tq = l & 3;
    int dbase = tq * 16;
    float4 o0 = {}, o1 = {}, o2 = {}, o3 = {};
    #pragma unroll
    for (int tt = 0; tt < 16; ++tt) {
        float p = sp[h2][tt];
        float4 v0 = *reinterpret_cast<const float4*>(&sv[tt][dbase + 0]);
        float4 v1 = *reinterpret_cast<const float4*>(&sv[tt][dbase + 4]);
        float4 v2 = *reinterpret_cast<const float4*>(&sv[tt][dbase + 8]);
        float4 v3 = *reinterpret_cast<const float4*>(&sv[tt][dbase + 12]);
        o0.x += p * v0.x; o0.y += p * v0.y; o0.z += p * v0.z; o0.w += p * v0.w;
        o1.x += p * v1.x; o1.y += p * v1.y; o1.z += p * v1.z; o1.w += p * v1.w;
        o2.x += p * v2.x; o2.y += p * v2.y; o2.z += p * v2.z; o2.w += p * v2.w;
        o3.x += p * v3.x; o3.y += p * v3.y; o3.z += p * v3.z; o3.w += p * v3.w;
    }
    ushort4* po = (ushort4*)(out + (size_t)pos * 1024 + h2 * 64 + dbase);
    ushort4 w0 = { f2bf(o0.x), f2bf(o0.y), f2bf(o0.z), f2bf(o0.w) };
    ushort4 w1 = { f2bf(o1.x), f2bf(o1.y), f2bf(o1.z), f2bf(o1.w) };
    ushort4 w2 = { f2bf(o2.x), f2bf(o2.y), f2bf(o2.z), f2bf(o2.w) };
    ushort4 w3 = { f2bf(o3.x), f2bf(o3.y), f2bf(o3.z), f2bf(o3.w) };
    po[0] = w0; po[1] = w1; po[2] = w2; po[3] = w3;
}

extern "C" void kernel_launch(void* const* d_in, const int* in_sizes, int n_in,
                              void* d_out, int out_size, void* d_ws, size_t ws_size,
                              hipStream_t stream) {
    const float* x     = (const float*)d_in[0];
    const float* w_qkv = (const float*)d_in[1];
    const float* b_qkv = (const float*)d_in[2];
    const float* w_o   = (const float*)d_in[3];
    const float* b_o   = (const float*)d_in[4];
    float* out = (float*)d_out;

    const int C = 1024, E = 1024;
    const int M = 16 * 1024;      // B*S = 16384
    const int N1 = 3 * E;         // 3072

    char* ws = (char*)d_ws;
    unsigned short* xb    = (unsigned short*)ws;            // M*C bf16
    unsigned short* wqkvT = xb    + (size_t)M * C;          // N1*C
    unsigned short* qkv   = wqkvT + (size_t)N1 * C;         // M*N1
    unsigned short* woT   = qkv   + (size_t)M * N1;         // E*E
    unsigned short* aout  = woT   + (size_t)E * E;          // M*E

    cvt_f32_bf16<<<2048, 256, 0, stream>>>(x, xb, M * C);
    dim3 tb(32, 8);
    transpose_cvt<<<dim3(N1 / 32, C / 32), tb, 0, stream>>>(w_qkv, wqkvT, C, N1);
    transpose_cvt<<<dim3(E / 32, E / 32), tb, 0, stream>>>(w_o, woT, E, E);

    // QKV: M=16384, N=3072, K=1024 -> 768 blocks
    gemm256<true><<<dim3((M / 256) * (N1 / 256)), 512, 0, stream>>>(
        xb, wqkvT, b_qkv, qkv, M, N1, C, N1 / 256);
    attn_kernel<<<M, 64, 0, stream>>>(qkv, aout);
    // O-proj: M=16384, N=1024 -> 256 blocks
    gemm256<false><<<dim3((M / 256) * (E / 256)), 512, 0, stream>>>(
        aout, woT, b_o, out, M, E, E, E / 256);
}